// Round 6
// baseline (370.351 us; speedup 1.0000x reference)
//
#include <hip/hip_runtime.h>
#include <stdint.h>

#define Bsz 4
#define Lsz 512
#define Dsz 768
#define Wsz 12
#define LWsz (Lsz * Wsz)        /* 6144  */
#define Nh   (Bsz * Lsz * Dsz)  /* 1572864 */
#define Npw  (2 * Dsz * Dsz)    /* 1179648 */
#define Npb  (2 * Dsz)          /* 1536 */
#define Now  (Dsz * 3 * Dsz)    /* 1769472 */
#define Nob  (Dsz)              /* 768 */
#define Nbt2 (Dsz * Wsz * Dsz)  /* 7077888 */
#define Nsp  (Bsz * Lsz * Wsz * 2) /* 49152 */
#define Nrp  (Bsz * Lsz * 2 * Dsz) /* 3145728 */
#define Nrc  (Bsz * Lsz * Wsz * Dsz) /* 18874368 */
#define Kconv (Wsz * Dsz)       /* 9216 */

#define POFF1 Nh
#define POFF2 (Nh + Npw)
#define POFF3 (Nh + Npw + Npb)
#define POFF4 (Nh + Npw + Npb + Now)
#define PTOT  (Nh + Npw + Npb + Now + Nob)   /* 4524288, all ranges %4==0 */

typedef __attribute__((ext_vector_type(8))) __bf16 bf16x8;
typedef __attribute__((ext_vector_type(4))) float f32x4;
typedef unsigned short u16;
typedef unsigned int u32;

#if __has_builtin(__builtin_amdgcn_mfma_f32_16x16x32_bf16)
#define HAVE_MFMA950 1
#else
#define HAVE_MFMA950 0
#endif

static __device__ __forceinline__ f32x4 mfma_bf16(bf16x8 a, bf16x8 b, f32x4 c) {
#if HAVE_MFMA950
    return __builtin_amdgcn_mfma_f32_16x16x32_bf16(a, b, c, 0, 0, 0);
#else
    return c;  // never executed on MI355X
#endif
}

static __device__ __forceinline__ float bf2f(u16 u) {
    union { u32 i; float f; } c; c.i = ((u32)u) << 16; return c.f;
}
static __device__ __forceinline__ u16 f2bf(float f) {
    union { float f; u32 i; } c; c.f = f;
    u32 u = c.i + 0x7FFFu + ((c.i >> 16) & 1u);
    return (u16)(u >> 16);
}

// ---------- dtype detection (verified R3/R4/R5) ----------
__global__ void detect_k(const u32* __restrict__ hw, const u32* __restrict__ sw,
                         int* __restrict__ flags) {
    __shared__ int cnt[2];
    if (threadIdx.x == 0) { cnt[0] = 0; cnt[1] = 0; }
    __syncthreads();
    int c0 = 0;
    for (int i = threadIdx.x; i < 2048; i += 256) {
        u32 e = (hw[i] >> 23) & 0xFFu;
        if (e >= 118u && e <= 130u) c0++;
    }
    int c1 = 0;
    for (int i = threadIdx.x; i < 512; i += 256)
        if (sw[2 * i + 1] == 0u) c1++;
    atomicAdd(&cnt[0], c0);
    atomicAdd(&cnt[1], c1);
    __syncthreads();
    if (threadIdx.x == 0) {
        flags[0] = (cnt[0] > 1024) ? 1 : 0;
        flags[1] = (cnt[1] >= 512) ? 1 : 0;
    }
}

// ---------- single merged pack for h, proj_w, proj_b, out_w, out_b ----------
// dst buffers are laid out contiguously in ws in exactly this order.
__global__ void pack_all(const void* __restrict__ s0, const void* __restrict__ s1,
                         const void* __restrict__ s2, const void* __restrict__ s3,
                         const void* __restrict__ s4, u16* __restrict__ dst,
                         const int* __restrict__ flags) {
    int i4 = blockIdx.x * 256 + threadIdx.x;
    if (i4 >= PTOT / 4) return;
    int i = i4 * 4;
    const void* src; int off;
    if (i < POFF1)      { src = s0; off = i; }
    else if (i < POFF2) { src = s1; off = i - POFF1; }
    else if (i < POFF3) { src = s2; off = i - POFF2; }
    else if (i < POFF4) { src = s3; off = i - POFF3; }
    else                { src = s4; off = i - POFF4; }
    ushort4 o;
    if (flags[0]) {
        const float* f = (const float*)src + off;
        o.x = f2bf(f[0]); o.y = f2bf(f[1]); o.z = f2bf(f[2]); o.w = f2bf(f[3]);
    } else {
        o = *(const ushort4*)((const u16*)src + off);
    }
    *(ushort4*)(dst + i) = o;
}

__global__ void pack_conv(const void* __restrict__ src, u16* __restrict__ dst,
                          const int* __restrict__ flags) {
    int idx = blockIdx.x * 256 + threadIdx.x;
    if (idx >= Nbt2) return;
    int c = idx % Dsz;
    int t = idx / Dsz;
    int j = t % Wsz;
    int o = t / Wsz;
    size_t s = (size_t)(o * Dsz + c) * Wsz + j;
    dst[idx] = flags[0] ? f2bf(((const float*)src)[s]) : ((const u16*)src)[s];
}

__global__ void pack_span(const int* __restrict__ sp, int* __restrict__ dst,
                          const int* __restrict__ flags) {
    int i = blockIdx.x * 256 + threadIdx.x;
    if (i >= Nsp) return;
    int v = flags[1] ? sp[2 * i] : sp[i];
    v = v < 0 ? 0 : (v > Lsz - 1 ? Lsz - 1 : v);
    dst[i] = v;
}

// ================= MFMA GEMM kernels (128x128 tile, 4 waves, 4x4 frags) =====
// Register-prefetch pipeline: next K-tile's global loads issue right after the
// first barrier, overlapping ds_read+MFMA; vmcnt drains only at next LDS store.
#define MF_PROLOG()                                                       \
    __shared__ __align__(16) u16 lds_a[128 * 40];                         \
    __shared__ __align__(16) u16 lds_b[128 * 40];                         \
    const int tid = threadIdx.x;                                          \
    const int lane = tid & 63;                                            \
    const int wave = tid >> 6;                                            \
    const int wm = wave & 1, wn = wave >> 1;                              \
    const int lcol = lane & 15;                                           \
    const int quad = lane >> 4;                                           \
    const int sr = tid >> 2;                                              \
    const int sc = (tid & 3) * 8;                                         \
    f32x4 acc[4][4] = {};

#define MF_STORE_LDS()                                                    \
    do {                                                                  \
        *(uint4*)&lds_a[sr * 40 + sc]        = ra0;                       \
        *(uint4*)&lds_a[(sr + 64) * 40 + sc] = ra1;                       \
        *(uint4*)&lds_b[sr * 40 + sc]        = rb0;                       \
        *(uint4*)&lds_b[(sr + 64) * 40 + sc] = rb1;                       \
    } while (0)

#define MF_FRAGS_MFMA()                                                   \
    do {                                                                  \
        bf16x8 af[4], bfr[4];                                             \
        _Pragma("unroll")                                                 \
        for (int _i = 0; _i < 4; ++_i)                                    \
            af[_i] = *(const bf16x8*)&lds_a[(wm * 64 + _i * 16 + lcol) * 40 + quad * 8]; \
        _Pragma("unroll")                                                 \
        for (int _j = 0; _j < 4; ++_j)                                    \
            bfr[_j] = *(const bf16x8*)&lds_b[(wn * 64 + _j * 16 + lcol) * 40 + quad * 8]; \
        _Pragma("unroll")                                                 \
        for (int _i = 0; _i < 4; ++_i)                                    \
            _Pragma("unroll")                                             \
            for (int _j = 0; _j < 4; ++_j)                                \
                acc[_i][_j] = mfma_bf16(af[_i], bfr[_j], acc[_i][_j]);    \
    } while (0)

// ---------- GEMM 1: rproj = relu(h @ proj_w^T + proj_b);  M2048 N1536 K768 --
__global__ __launch_bounds__(256) void mgemm_proj(const u16* __restrict__ A,
                                                  const u16* __restrict__ Bt,
                                                  const u16* __restrict__ bias,
                                                  u16* __restrict__ C) {
    MF_PROLOG();
    const int bm = blockIdx.x * 128, bn = blockIdx.y * 128;
    const u16* a0 = A + (size_t)(bm + sr) * 768 + sc;
    const u16* b0 = Bt + (size_t)(bn + sr) * 768 + sc;
    uint4 ra0 = *(const uint4*)(a0);
    uint4 ra1 = *(const uint4*)(a0 + (size_t)64 * 768);
    uint4 rb0 = *(const uint4*)(b0);
    uint4 rb1 = *(const uint4*)(b0 + (size_t)64 * 768);
    for (int kb = 0; kb < 768; kb += 32) {
        MF_STORE_LDS();
        __syncthreads();
        if (kb + 32 < 768) {
            ra0 = *(const uint4*)(a0 + kb + 32);
            ra1 = *(const uint4*)(a0 + (size_t)64 * 768 + kb + 32);
            rb0 = *(const uint4*)(b0 + kb + 32);
            rb1 = *(const uint4*)(b0 + (size_t)64 * 768 + kb + 32);
        }
        MF_FRAGS_MFMA();
        __syncthreads();
    }
#pragma unroll
    for (int i = 0; i < 4; ++i)
#pragma unroll
        for (int j = 0; j < 4; ++j) {
            int col = bn + wn * 64 + j * 16 + lcol;
            float bv = bf2f(bias[col]);
#pragma unroll
            for (int r = 0; r < 4; ++r) {
                int row = bm + wm * 64 + i * 16 + quad * 4 + r;
                float v = acc[i][j][r] + bv;
                C[(size_t)row * 1536 + col] = f2bf(v > 0.f ? v : 0.f);
            }
        }
}

// ---------- GEMM 2a: per-j conv contributions (raw, no relu) ----------------
__global__ __launch_bounds__(256) void mgemm_convc(const u16* __restrict__ H,
                                                   const u16* __restrict__ Bt2,
                                                   u16* __restrict__ Cv) {
    MF_PROLOG();
    const int j = blockIdx.z;
    const int bm = blockIdx.x * 128, bn = blockIdx.y * 128;
    const int row0 = bm + sr, row1 = row0 + 64;
    const int l0 = row0 & (Lsz - 1), l1 = row1 & (Lsz - 1);
    const u16* a0 = H + (size_t)(row0 + j) * 768 + sc;
    const u16* a1 = H + (size_t)(row1 + j) * 768 + sc;
    const u16* b0 = Bt2 + (size_t)(bn + sr) * Kconv + (size_t)j * 768 + sc;
    const uint4 zero = {0u, 0u, 0u, 0u};
    const bool v0 = (l0 + j < Lsz), v1 = (l1 + j < Lsz);
    uint4 ra0 = v0 ? *(const uint4*)(a0) : zero;
    uint4 ra1 = v1 ? *(const uint4*)(a1) : zero;
    uint4 rb0 = *(const uint4*)(b0);
    uint4 rb1 = *(const uint4*)(b0 + (size_t)64 * Kconv);
    for (int kb = 0; kb < 768; kb += 32) {
        MF_STORE_LDS();
        __syncthreads();
        if (kb + 32 < 768) {
            ra0 = v0 ? *(const uint4*)(a0 + kb + 32) : zero;
            ra1 = v1 ? *(const uint4*)(a1 + kb + 32) : zero;
            rb0 = *(const uint4*)(b0 + kb + 32);
            rb1 = *(const uint4*)(b0 + (size_t)64 * Kconv + kb + 32);
        }
        MF_FRAGS_MFMA();
        __syncthreads();
    }
#pragma unroll
    for (int i = 0; i < 4; ++i)
#pragma unroll
        for (int jj = 0; jj < 4; ++jj) {
            int col = bn + wn * 64 + jj * 16 + lcol;
#pragma unroll
            for (int r = 0; r < 4; ++r) {
                int row = bm + wm * 64 + i * 16 + quad * 4 + r;
                Cv[((size_t)row * Wsz + j) * 768 + col] = f2bf(acc[i][jj][r]);
            }
        }
}

// ---------- GEMM 2b: in-place running sum over j + relu --------------------
__global__ __launch_bounds__(256) void cumsum_relu(u16* __restrict__ Cv) {
    int idx = blockIdx.x * 256 + threadIdx.x;
    const int total = (Bsz * Lsz) * (Dsz / 8);
    if (idx >= total) return;
    int m = idx / (Dsz / 8);
    int c = (idx % (Dsz / 8)) * 8;
    u16* p = Cv + (size_t)m * Wsz * 768 + c;
    float s[8] = {0.f, 0.f, 0.f, 0.f, 0.f, 0.f, 0.f, 0.f};
#pragma unroll
    for (int j = 0; j < Wsz; ++j) {
        uint4 t = *(const uint4*)(p + (size_t)j * 768);
        const u16* q = (const u16*)&t;
        uint4 o;
        u16* qo = (u16*)&o;
#pragma unroll
        for (int i = 0; i < 8; ++i) {
            s[i] += bf2f(q[i]);
            qo[i] = f2bf(s[i] > 0.f ? s[i] : 0.f);
        }
        *(uint4*)(p + (size_t)j * 768) = o;
    }
}

// ---------- GEMM 3: out = relu(relu(cat) @ out_w^T + out_b) -----------------
// M24576 (gathered) N768 K2304 over 3 segments, flattened K-loop w/ prefetch.
__global__ __launch_bounds__(256) void mgemm_out(const u16* __restrict__ RP,
                                                 const u16* __restrict__ RC,
                                                 const int* __restrict__ SPn,
                                                 const u16* __restrict__ Bt,
                                                 const u16* __restrict__ bias,
                                                 void* __restrict__ out,
                                                 const int* __restrict__ flags) {
    MF_PROLOG();
    __shared__ u32 offs[3][128];
    const int bm = blockIdx.x * 128, bn = blockIdx.y * 128;
    if (tid < 128) {
        int n = bm + tid;
        int b = n / LWsz;
        int s0 = SPn[2 * n], s1 = SPn[2 * n + 1];
        offs[0][tid] = (u32)((b * Lsz + s0) * 1536);
        offs[1][tid] = (u32)((b * Lsz + s1) * 1536 + 768);
        offs[2][tid] = (u32)(n * 768);
    }
    __syncthreads();
    // keep all gather offsets in registers so prefetch needs no LDS reads
    const u32 oa0 = offs[0][sr], oa1 = offs[1][sr], oa2 = offs[2][sr];
    const u32 ob0 = offs[0][sr + 64], ob1 = offs[1][sr + 64], ob2 = offs[2][sr + 64];
    const u16* b0 = Bt + (size_t)(bn + sr) * 2304 + sc;

    uint4 ra0, ra1, rb0, rb1;
    {   // k = 0 -> seg 0
        ra0 = *(const uint4*)(RP + (size_t)oa0 + sc);
        ra1 = *(const uint4*)(RP + (size_t)ob0 + sc);
        rb0 = *(const uint4*)(b0);
        rb1 = *(const uint4*)(b0 + (size_t)64 * 2304);
    }
    for (int kb = 0; kb < 2304; kb += 32) {
        MF_STORE_LDS();
        __syncthreads();
        const int k = kb + 32;
        if (k < 2304) {
            const int seg = (k >= 1536) ? 2 : ((k >= 768) ? 1 : 0);
            const int off = k - seg * 768 + sc;
            const u16* src = (seg == 2) ? RC : RP;
            const u32 oa = (seg == 2) ? oa2 : ((seg == 1) ? oa1 : oa0);
            const u32 ob = (seg == 2) ? ob2 : ((seg == 1) ? ob1 : ob0);
            ra0 = *(const uint4*)(src + (size_t)oa + off);
            ra1 = *(const uint4*)(src + (size_t)ob + off);
            rb0 = *(const uint4*)(b0 + k);
            rb1 = *(const uint4*)(b0 + (size_t)64 * 2304 + k);
        }
        MF_FRAGS_MFMA();
        __syncthreads();
    }
    const int isf32 = flags[0];
#pragma unroll
    for (int i = 0; i < 4; ++i)
#pragma unroll
        for (int j = 0; j < 4; ++j) {
            int col = bn + wn * 64 + j * 16 + lcol;
            float bv = bf2f(bias[col]);
#pragma unroll
            for (int r = 0; r < 4; ++r) {
                int row = bm + wm * 64 + i * 16 + quad * 4 + r;
                float v = acc[i][j][r] + bv;
                v = v > 0.f ? v : 0.f;
                if (isf32) ((float*)out)[(size_t)row * 768 + col] = v;
                else       ((u16*)out)[(size_t)row * 768 + col] = f2bf(v);
            }
        }
}

extern "C" void kernel_launch(void* const* d_in, const int* in_sizes, int n_in,
                              void* d_out, int out_size, void* d_ws, size_t ws_size,
                              hipStream_t stream) {
    const void* h      = d_in[0];
    const void* span   = d_in[1];
    const void* proj_w = d_in[2];
    const void* proj_b = d_in[3];
    const void* conv_w = d_in[4];
    const void* out_w  = d_in[5];
    const void* out_b  = d_in[6];

    char* p = (char*)d_ws;
    int* flags = (int*)p;                 p += 64;
    u16* ch    = (u16*)p;                 p += (size_t)Nh   * 2;   // pack_all dst base
    u16* cpw   = (u16*)p;                 p += (size_t)Npw  * 2;
    u16* cpb   = (u16*)p;                 p += (size_t)Npb  * 2;
    u16* cow   = (u16*)p;                 p += (size_t)Now  * 2;
    u16* cob   = (u16*)p;                 p += (size_t)Nob  * 2;
    u16* bt2   = (u16*)p;                 p += (size_t)Nbt2 * 2;
    u16* rproj = (u16*)p;                 p += (size_t)Nrp  * 2;
    u16* rconv = (u16*)p;                 p += (size_t)Nrc  * 2;
    int* cspan = (int*)p;

    detect_k<<<1, 256, 0, stream>>>((const u32*)h, (const u32*)span, flags);

    pack_all<<<(PTOT / 4 + 255) / 256, 256, 0, stream>>>(h, proj_w, proj_b,
                                                         out_w, out_b, ch, flags);
    pack_conv<<<(Nbt2 + 255) / 256, 256, 0, stream>>>(conv_w, bt2, flags);
    pack_span<<<(Nsp + 255) / 256, 256, 0, stream>>>((const int*)span, cspan, flags);

    mgemm_proj<<<dim3(16, 12), 256, 0, stream>>>(ch, cpw, cpb, rproj);
    mgemm_convc<<<dim3(16, 6, 12), 256, 0, stream>>>(ch, bt2, rconv);
    cumsum_relu<<<((Bsz * Lsz) * (Dsz / 8) + 255) / 256, 256, 0, stream>>>(rconv);
    mgemm_out<<<dim3(192, 6), 256, 0, stream>>>(rproj, rconv, cspan, cow, cob,
                                                d_out, flags);
}

// Round 7
// 345.339 us; speedup vs baseline: 1.0724x; 1.0724x over previous
//
#include <hip/hip_runtime.h>
#include <stdint.h>

#define Bsz 4
#define Lsz 512
#define Dsz 768
#define Wsz 12
#define LWsz (Lsz * Wsz)        /* 6144  */
#define Nh   (Bsz * Lsz * Dsz)  /* 1572864 */
#define Npw  (2 * Dsz * Dsz)    /* 1179648 */
#define Npb  (2 * Dsz)          /* 1536 */
#define Now  (Dsz * 3 * Dsz)    /* 1769472 */
#define Nob  (Dsz)              /* 768 */
#define Nbt2 (Dsz * Wsz * Dsz)  /* 7077888 */
#define Nsp  (Bsz * Lsz * Wsz * 2) /* 49152 */
#define Nrp  (Bsz * Lsz * 2 * Dsz) /* 3145728 */
#define Nrc  (Bsz * Lsz * Wsz * Dsz) /* 18874368 */
#define Kconv (Wsz * Dsz)       /* 9216 */

#define POFF1 Nh
#define POFF2 (Nh + Npw)
#define POFF3 (Nh + Npw + Npb)
#define POFF4 (Nh + Npw + Npb + Now)
#define PTOT  (Nh + Npw + Npb + Now + Nob)

typedef __attribute__((ext_vector_type(8))) __bf16 bf16x8;
typedef __attribute__((ext_vector_type(4))) float f32x4;
typedef unsigned short u16;
typedef unsigned int u32;

#if __has_builtin(__builtin_amdgcn_mfma_f32_16x16x32_bf16)
#define HAVE_MFMA950 1
#else
#define HAVE_MFMA950 0
#endif

#if __has_builtin(__builtin_amdgcn_global_load_lds)
#define HAVE_GLL 1
#else
#define HAVE_GLL 0
#endif

static __device__ __forceinline__ f32x4 mfma_bf16(bf16x8 a, bf16x8 b, f32x4 c) {
#if HAVE_MFMA950
    return __builtin_amdgcn_mfma_f32_16x16x32_bf16(a, b, c, 0, 0, 0);
#else
    return c;  // never executed on MI355X
#endif
}

// async global->LDS, 16 B per lane; LDS dest must equal waveBase + lane*16.
static __device__ __forceinline__ void gll16(const u16* g, u16* l) {
#if HAVE_GLL
    __builtin_amdgcn_global_load_lds(
        (const __attribute__((address_space(1))) u32*)g,
        (__attribute__((address_space(3))) u32*)l, 16, 0, 0);
#else
    *(uint4*)l = *(const uint4*)g;  // never executed on MI355X
#endif
}

static __device__ __forceinline__ float bf2f(u16 u) {
    union { u32 i; float f; } c; c.i = ((u32)u) << 16; return c.f;
}
static __device__ __forceinline__ u16 f2bf(float f) {
    union { float f; u32 i; } c; c.f = f;
    u32 u = c.i + 0x7FFFu + ((c.i >> 16) & 1u);
    return (u16)(u >> 16);
}

// ---------- dtype detection (verified R3..R6) ----------
__global__ void detect_k(const u32* __restrict__ hw, const u32* __restrict__ sw,
                         int* __restrict__ flags) {
    __shared__ int cnt[2];
    if (threadIdx.x == 0) { cnt[0] = 0; cnt[1] = 0; }
    __syncthreads();
    int c0 = 0;
    for (int i = threadIdx.x; i < 2048; i += 256) {
        u32 e = (hw[i] >> 23) & 0xFFu;
        if (e >= 118u && e <= 130u) c0++;
    }
    int c1 = 0;
    for (int i = threadIdx.x; i < 512; i += 256)
        if (sw[2 * i + 1] == 0u) c1++;
    atomicAdd(&cnt[0], c0);
    atomicAdd(&cnt[1], c1);
    __syncthreads();
    if (threadIdx.x == 0) {
        flags[0] = (cnt[0] > 1024) ? 1 : 0;
        flags[1] = (cnt[1] >= 512) ? 1 : 0;
    }
}

__global__ void pack_all(const void* __restrict__ s0, const void* __restrict__ s1,
                         const void* __restrict__ s2, const void* __restrict__ s3,
                         const void* __restrict__ s4, u16* __restrict__ dst,
                         const int* __restrict__ flags) {
    int i4 = blockIdx.x * 256 + threadIdx.x;
    if (i4 >= PTOT / 4) return;
    int i = i4 * 4;
    const void* src; int off;
    if (i < POFF1)      { src = s0; off = i; }
    else if (i < POFF2) { src = s1; off = i - POFF1; }
    else if (i < POFF3) { src = s2; off = i - POFF2; }
    else if (i < POFF4) { src = s3; off = i - POFF3; }
    else                { src = s4; off = i - POFF4; }
    ushort4 o;
    if (flags[0]) {
        const float* f = (const float*)src + off;
        o.x = f2bf(f[0]); o.y = f2bf(f[1]); o.z = f2bf(f[2]); o.w = f2bf(f[3]);
    } else {
        o = *(const ushort4*)((const u16*)src + off);
    }
    *(ushort4*)(dst + i) = o;
}

__global__ void pack_conv(const void* __restrict__ src, u16* __restrict__ dst,
                          const int* __restrict__ flags) {
    int idx = blockIdx.x * 256 + threadIdx.x;
    if (idx >= Nbt2) return;
    int c = idx % Dsz;
    int t = idx / Dsz;
    int j = t % Wsz;
    int o = t / Wsz;
    size_t s = (size_t)(o * Dsz + c) * Wsz + j;
    dst[idx] = flags[0] ? f2bf(((const float*)src)[s]) : ((const u16*)src)[s];
}

__global__ void pack_span(const int* __restrict__ sp, int* __restrict__ dst,
                          const int* __restrict__ flags) {
    int i = blockIdx.x * 256 + threadIdx.x;
    if (i >= Nsp) return;
    int v = flags[1] ? sp[2 * i] : sp[i];
    v = v < 0 ? 0 : (v > Lsz - 1 ? Lsz - 1 : v);
    dst[i] = v;
}

// ============ MFMA GEMMs: 128x128 tile, 4 waves, global_load_lds staging ====
// LDS tiles UNPADDED [row][k] u16 stride 32 (64 B/row) — required by
// global_load_lds's dest rule (waveBase + lane*16). Staging dest = tid*16 B
// within each 64-row half-region; global source mapping identical to R4-R6.
#define MF_PROLOG()                                                       \
    __shared__ __align__(16) u16 lds_a[128 * 32];                         \
    __shared__ __align__(16) u16 lds_b[128 * 32];                         \
    const int tid = threadIdx.x;                                          \
    const int lane = tid & 63;                                            \
    const int wave = tid >> 6;                                            \
    const int wm = wave & 1, wn = wave >> 1;                              \
    const int lcol = lane & 15;                                           \
    const int quad = lane >> 4;                                           \
    const int sr = tid >> 2;                                              \
    const int sc = (tid & 3) * 8;                                         \
    u16* const la  = lds_a + tid * 8;                                     \
    u16* const la2 = lds_a + 64 * 32 + tid * 8;                           \
    u16* const lb  = lds_b + tid * 8;                                     \
    u16* const lb2 = lds_b + 64 * 32 + tid * 8;                           \
    f32x4 acc[4][4] = {};

#define MF_FRAGS_MFMA()                                                   \
    do {                                                                  \
        bf16x8 af[4], bfr[4];                                             \
        _Pragma("unroll")                                                 \
        for (int _i = 0; _i < 4; ++_i)                                    \
            af[_i] = *(const bf16x8*)&lds_a[(wm * 64 + _i * 16 + lcol) * 32 + quad * 8]; \
        _Pragma("unroll")                                                 \
        for (int _j = 0; _j < 4; ++_j)                                    \
            bfr[_j] = *(const bf16x8*)&lds_b[(wn * 64 + _j * 16 + lcol) * 32 + quad * 8]; \
        _Pragma("unroll")                                                 \
        for (int _i = 0; _i < 4; ++_i)                                    \
            _Pragma("unroll")                                             \
            for (int _j = 0; _j < 4; ++_j)                                \
                acc[_i][_j] = mfma_bf16(af[_i], bfr[_j], acc[_i][_j]);    \
    } while (0)

// ---------- GEMM 1: rproj = relu(h @ proj_w^T + proj_b);  M2048 N1536 K768 --
__global__ __launch_bounds__(256) void mgemm_proj(const u16* __restrict__ A,
                                                  const u16* __restrict__ Bt,
                                                  const u16* __restrict__ bias,
                                                  u16* __restrict__ C) {
    MF_PROLOG();
    const int bm = blockIdx.x * 128, bn = blockIdx.y * 128;
    const u16* a0 = A + (size_t)(bm + sr) * 768 + sc;
    const u16* b0 = Bt + (size_t)(bn + sr) * 768 + sc;
    for (int kb = 0; kb < 768; kb += 32) {
        gll16(a0 + kb, la);
        gll16(a0 + (size_t)64 * 768 + kb, la2);
        gll16(b0 + kb, lb);
        gll16(b0 + (size_t)64 * 768 + kb, lb2);
        __syncthreads();
        MF_FRAGS_MFMA();
        __syncthreads();
    }
#pragma unroll
    for (int i = 0; i < 4; ++i)
#pragma unroll
        for (int j = 0; j < 4; ++j) {
            int col = bn + wn * 64 + j * 16 + lcol;
            float bv = bf2f(bias[col]);
#pragma unroll
            for (int r = 0; r < 4; ++r) {
                int row = bm + wm * 64 + i * 16 + quad * 4 + r;
                float v = acc[i][j][r] + bv;
                C[(size_t)row * 1536 + col] = f2bf(v > 0.f ? v : 0.f);
            }
        }
}

// ---------- GEMM 2a: per-j conv contributions (raw, no relu) ----------------
__global__ __launch_bounds__(256) void mgemm_convc(const u16* __restrict__ H,
                                                   const u16* __restrict__ Bt2,
                                                   u16* __restrict__ Cv) {
    MF_PROLOG();
    const int j = blockIdx.z;
    const int bm = blockIdx.x * 128, bn = blockIdx.y * 128;
    const int row0 = bm + sr, row1 = row0 + 64;
    const int l0 = row0 & (Lsz - 1), l1 = row1 & (Lsz - 1);
    const u16* a0 = H + (size_t)(row0 + j) * 768 + sc;
    const u16* a1 = H + (size_t)(row1 + j) * 768 + sc;
    const u16* b0 = Bt2 + (size_t)(bn + sr) * Kconv + (size_t)j * 768 + sc;
    const bool v0 = (l0 + j < Lsz), v1 = (l1 + j < Lsz);
    // invalid rows: zero once; never written by gll afterwards (validity is
    // K-invariant), so they stay zero for every K-step.
    const uint4 zero = {0u, 0u, 0u, 0u};
    if (!v0) *(uint4*)la  = zero;
    if (!v1) *(uint4*)la2 = zero;
    for (int kb = 0; kb < 768; kb += 32) {
        if (v0) gll16(a0 + kb, la);
        if (v1) gll16(a1 + kb, la2);
        gll16(b0 + kb, lb);
        gll16(b0 + (size_t)64 * Kconv + kb, lb2);
        __syncthreads();
        MF_FRAGS_MFMA();
        __syncthreads();
    }
#pragma unroll
    for (int i = 0; i < 4; ++i)
#pragma unroll
        for (int jj = 0; jj < 4; ++jj) {
            int col = bn + wn * 64 + jj * 16 + lcol;
#pragma unroll
            for (int r = 0; r < 4; ++r) {
                int row = bm + wm * 64 + i * 16 + quad * 4 + r;
                Cv[((size_t)row * Wsz + j) * 768 + col] = f2bf(acc[i][jj][r]);
            }
        }
}

// ---------- GEMM 2b: in-place running sum over j + relu --------------------
__global__ __launch_bounds__(256) void cumsum_relu(u16* __restrict__ Cv) {
    int idx = blockIdx.x * 256 + threadIdx.x;
    const int total = (Bsz * Lsz) * (Dsz / 8);
    if (idx >= total) return;
    int m = idx / (Dsz / 8);
    int c = (idx % (Dsz / 8)) * 8;
    u16* p = Cv + (size_t)m * Wsz * 768 + c;
    float s[8] = {0.f, 0.f, 0.f, 0.f, 0.f, 0.f, 0.f, 0.f};
#pragma unroll
    for (int j = 0; j < Wsz; ++j) {
        uint4 t = *(const uint4*)(p + (size_t)j * 768);
        const u16* q = (const u16*)&t;
        uint4 o;
        u16* qo = (u16*)&o;
#pragma unroll
        for (int i = 0; i < 8; ++i) {
            s[i] += bf2f(q[i]);
            qo[i] = f2bf(s[i] > 0.f ? s[i] : 0.f);
        }
        *(uint4*)(p + (size_t)j * 768) = o;
    }
}

// ---------- GEMM 3: out = relu(relu(cat) @ out_w^T + out_b) -----------------
// M24576 (gathered) N768 K2304, 3 segments; gathers feed per-lane gll addrs.
__global__ __launch_bounds__(256) void mgemm_out(const u16* __restrict__ RP,
                                                 const u16* __restrict__ RC,
                                                 const int* __restrict__ SPn,
                                                 const u16* __restrict__ Bt,
                                                 const u16* __restrict__ bias,
                                                 void* __restrict__ out,
                                                 const int* __restrict__ flags) {
    MF_PROLOG();
    __shared__ u32 offs[3][128];
    const int bm = blockIdx.x * 128, bn = blockIdx.y * 128;
    if (tid < 128) {
        int n = bm + tid;
        int b = n / LWsz;
        int s0 = SPn[2 * n], s1 = SPn[2 * n + 1];
        offs[0][tid] = (u32)((b * Lsz + s0) * 1536);
        offs[1][tid] = (u32)((b * Lsz + s1) * 1536 + 768);
        offs[2][tid] = (u32)(n * 768);
    }
    __syncthreads();
    const u32 oa0 = offs[0][sr], oa1 = offs[1][sr], oa2 = offs[2][sr];
    const u32 ob0 = offs[0][sr + 64], ob1 = offs[1][sr + 64], ob2 = offs[2][sr + 64];
    const u16* b0 = Bt + (size_t)(bn + sr) * 2304 + sc;
    for (int kb = 0; kb < 2304; kb += 32) {
        const int seg = (kb >= 1536) ? 2 : ((kb >= 768) ? 1 : 0);
        const int koff = kb - seg * 768 + sc;
        const u16* src = (seg == 2) ? RC : RP;
        const u32 oa = (seg == 2) ? oa2 : ((seg == 1) ? oa1 : oa0);
        const u32 ob = (seg == 2) ? ob2 : ((seg == 1) ? ob1 : ob0);
        gll16(src + (size_t)oa + koff, la);
        gll16(src + (size_t)ob + koff, la2);
        gll16(b0 + kb, lb);
        gll16(b0 + (size_t)64 * 2304 + kb, lb2);
        __syncthreads();
        MF_FRAGS_MFMA();
        __syncthreads();
    }
    const int isf32 = flags[0];
#pragma unroll
    for (int i = 0; i < 4; ++i)
#pragma unroll
        for (int j = 0; j < 4; ++j) {
            int col = bn + wn * 64 + j * 16 + lcol;
            float bv = bf2f(bias[col]);
#pragma unroll
            for (int r = 0; r < 4; ++r) {
                int row = bm + wm * 64 + i * 16 + quad * 4 + r;
                float v = acc[i][j][r] + bv;
                v = v > 0.f ? v : 0.f;
                if (isf32) ((float*)out)[(size_t)row * 768 + col] = v;
                else       ((u16*)out)[(size_t)row * 768 + col] = f2bf(v);
            }
        }
}

extern "C" void kernel_launch(void* const* d_in, const int* in_sizes, int n_in,
                              void* d_out, int out_size, void* d_ws, size_t ws_size,
                              hipStream_t stream) {
    const void* h      = d_in[0];
    const void* span   = d_in[1];
    const void* proj_w = d_in[2];
    const void* proj_b = d_in[3];
    const void* conv_w = d_in[4];
    const void* out_w  = d_in[5];
    const void* out_b  = d_in[6];

    char* p = (char*)d_ws;
    int* flags = (int*)p;                 p += 64;
    u16* ch    = (u16*)p;                 p += (size_t)Nh   * 2;   // pack_all dst base
    u16* cpw   = (u16*)p;                 p += (size_t)Npw  * 2;
    u16* cpb   = (u16*)p;                 p += (size_t)Npb  * 2;
    u16* cow   = (u16*)p;                 p += (size_t)Now  * 2;
    u16* cob   = (u16*)p;                 p += (size_t)Nob  * 2;
    u16* bt2   = (u16*)p;                 p += (size_t)Nbt2 * 2;
    u16* rproj = (u16*)p;                 p += (size_t)Nrp  * 2;
    u16* rconv = (u16*)p;                 p += (size_t)Nrc  * 2;
    int* cspan = (int*)p;

    detect_k<<<1, 256, 0, stream>>>((const u32*)h, (const u32*)span, flags);

    pack_all<<<(PTOT / 4 + 255) / 256, 256, 0, stream>>>(h, proj_w, proj_b,
                                                         out_w, out_b, ch, flags);
    pack_conv<<<(Nbt2 + 255) / 256, 256, 0, stream>>>(conv_w, bt2, flags);
    pack_span<<<(Nsp + 255) / 256, 256, 0, stream>>>((const int*)span, cspan, flags);

    mgemm_proj<<<dim3(16, 12), 256, 0, stream>>>(ch, cpw, cpb, rproj);
    mgemm_convc<<<dim3(16, 6, 12), 256, 0, stream>>>(ch, bt2, rconv);
    cumsum_relu<<<((Bsz * Lsz) * (Dsz / 8) + 255) / 256, 256, 0, stream>>>(rconv);
    mgemm_out<<<dim3(192, 6), 256, 0, stream>>>(rproj, rconv, cspan, cow, cob,
                                                d_out, flags);
}

// Round 9
// 332.088 us; speedup vs baseline: 1.1152x; 1.0399x over previous
//
#include <hip/hip_runtime.h>
#include <stdint.h>

#define Bsz 4
#define Lsz 512
#define Dsz 768
#define Wsz 12
#define LWsz (Lsz * Wsz)        /* 6144  */
#define Nh   (Bsz * Lsz * Dsz)  /* 1572864 */
#define Npw  (2 * Dsz * Dsz)    /* 1179648 */
#define Npb  (2 * Dsz)          /* 1536 */
#define Now  (Dsz * 3 * Dsz)    /* 1769472 */
#define Nob  (Dsz)              /* 768 */
#define Nbt2 (Dsz * Wsz * Dsz)  /* 7077888 */
#define Nsp  (Bsz * Lsz * Wsz * 2) /* 49152 */
#define Nrp  (Bsz * Lsz * 2 * Dsz) /* 3145728 */
#define Nrc  (Bsz * Lsz * Wsz * Dsz) /* 18874368 */
#define Kconv (Wsz * Dsz)       /* 9216 */

#define POFF1 Nh
#define POFF2 (Nh + Npw)
#define POFF3 (Nh + Npw + Npb)
#define POFF4 (Nh + Npw + Npb + Now)
#define PTOT  (Nh + Npw + Npb + Now + Nob)

typedef __attribute__((ext_vector_type(8))) __bf16 bf16x8;
typedef __attribute__((ext_vector_type(4))) float f32x4;
typedef unsigned short u16;
typedef unsigned int u32;

#if __has_builtin(__builtin_amdgcn_mfma_f32_16x16x32_bf16)
#define HAVE_MFMA950 1
#else
#define HAVE_MFMA950 0
#endif

#if __has_builtin(__builtin_amdgcn_global_load_lds)
#define HAVE_GLL 1
#else
#define HAVE_GLL 0
#endif

static __device__ __forceinline__ f32x4 mfma_bf16(bf16x8 a, bf16x8 b, f32x4 c) {
#if HAVE_MFMA950
    return __builtin_amdgcn_mfma_f32_16x16x32_bf16(a, b, c, 0, 0, 0);
#else
    return c;  // never executed on MI355X
#endif
}

static __device__ __forceinline__ void gll16(const u16* g, u16* l) {
#if HAVE_GLL
    __builtin_amdgcn_global_load_lds(
        (const __attribute__((address_space(1))) u32*)g,
        (__attribute__((address_space(3))) u32*)l, 16, 0, 0);
#else
    *(uint4*)l = *(const uint4*)g;  // never executed on MI355X
#endif
}

static __device__ __forceinline__ float bf2f(u16 u) {
    union { u32 i; float f; } c; c.i = ((u32)u) << 16; return c.f;
}
static __device__ __forceinline__ u16 f2bf(float f) {
    union { float f; u32 i; } c; c.f = f;
    u32 u = c.i + 0x7FFFu + ((c.i >> 16) & 1u);
    return (u16)(u >> 16);
}

// ---------- dtype detection (verified R3..R7) ----------
__global__ void detect_k(const u32* __restrict__ hw, const u32* __restrict__ sw,
                         int* __restrict__ flags) {
    __shared__ int cnt[2];
    if (threadIdx.x == 0) { cnt[0] = 0; cnt[1] = 0; }
    __syncthreads();
    int c0 = 0;
    for (int i = threadIdx.x; i < 2048; i += 256) {
        u32 e = (hw[i] >> 23) & 0xFFu;
        if (e >= 118u && e <= 130u) c0++;
    }
    int c1 = 0;
    for (int i = threadIdx.x; i < 512; i += 256)
        if (sw[2 * i + 1] == 0u) c1++;
    atomicAdd(&cnt[0], c0);
    atomicAdd(&cnt[1], c1);
    __syncthreads();
    if (threadIdx.x == 0) {
        flags[0] = (cnt[0] > 1024) ? 1 : 0;
        flags[1] = (cnt[1] >= 512) ? 1 : 0;
    }
}

__global__ void pack_all(const void* __restrict__ s0, const void* __restrict__ s1,
                         const void* __restrict__ s2, const void* __restrict__ s3,
                         const void* __restrict__ s4, u16* __restrict__ dst,
                         const int* __restrict__ flags) {
    int i4 = blockIdx.x * 256 + threadIdx.x;
    if (i4 >= PTOT / 4) return;
    int i = i4 * 4;
    const void* src; int off;
    if (i < POFF1)      { src = s0; off = i; }
    else if (i < POFF2) { src = s1; off = i - POFF1; }
    else if (i < POFF3) { src = s2; off = i - POFF2; }
    else if (i < POFF4) { src = s3; off = i - POFF3; }
    else                { src = s4; off = i - POFF4; }
    ushort4 o;
    if (flags[0]) {
        const float* f = (const float*)src + off;
        o.x = f2bf(f[0]); o.y = f2bf(f[1]); o.z = f2bf(f[2]); o.w = f2bf(f[3]);
    } else {
        o = *(const ushort4*)((const u16*)src + off);
    }
    *(ushort4*)(dst + i) = o;
}

__global__ void pack_conv(const void* __restrict__ src, u16* __restrict__ dst,
                          const int* __restrict__ flags) {
    int idx = blockIdx.x * 256 + threadIdx.x;
    if (idx >= Nbt2) return;
    int c = idx % Dsz;
    int t = idx / Dsz;
    int j = t % Wsz;
    int o = t / Wsz;
    size_t s = (size_t)(o * Dsz + c) * Wsz + j;
    dst[idx] = flags[0] ? f2bf(((const float*)src)[s]) : ((const u16*)src)[s];
}

__global__ void pack_span(const int* __restrict__ sp, int* __restrict__ dst,
                          const int* __restrict__ flags) {
    int i = blockIdx.x * 256 + threadIdx.x;
    if (i >= Nsp) return;
    int v = flags[1] ? sp[2 * i] : sp[i];
    v = v < 0 ? 0 : (v > Lsz - 1 ? Lsz - 1 : v);
    dst[i] = v;
}

// ===== MFMA GEMMs: 128x128 tile, gll staging, double-buffered LDS ==========
// Unpadded [row][k] u16 stride 32 tiles, 2 buffers of 4096 u16 each per matrix.
// One __syncthreads per K-step: stage(next buf) -> compute(cur buf) -> barrier.
#define MF_IDS()                                                          \
    const int tid = threadIdx.x;                                          \
    const int lane = tid & 63;                                            \
    const int wave = tid >> 6;                                            \
    const int wm = wave & 1, wn = wave >> 1;                              \
    const int lcol = lane & 15;                                           \
    const int quad = lane >> 4;                                           \
    const int sr = tid >> 2;                                              \
    const int sc = (tid & 3) * 8;                                         \
    f32x4 acc[4][4] = {};

#define MF_MFMA_BUF(cur)                                                  \
    do {                                                                  \
        const u16* Ab = lds_a + (cur) * 4096;                             \
        const u16* Bb = lds_b + (cur) * 4096;                             \
        bf16x8 af[4], bfr[4];                                             \
        _Pragma("unroll")                                                 \
        for (int _i = 0; _i < 4; ++_i)                                    \
            af[_i] = *(const bf16x8*)&Ab[(wm * 64 + _i * 16 + lcol) * 32 + quad * 8]; \
        _Pragma("unroll")                                                 \
        for (int _j = 0; _j < 4; ++_j)                                    \
            bfr[_j] = *(const bf16x8*)&Bb[(wn * 64 + _j * 16 + lcol) * 32 + quad * 8]; \
        _Pragma("unroll")                                                 \
        for (int _i = 0; _i < 4; ++_i)                                    \
            _Pragma("unroll")                                             \
            for (int _j = 0; _j < 4; ++_j)                                \
                acc[_i][_j] = mfma_bf16(af[_i], bfr[_j], acc[_i][_j]);    \
    } while (0)

// ---------- GEMM 1: rproj = relu(h @ proj_w^T + proj_b);  M2048 N1536 K768 --
__global__ __launch_bounds__(256) void mgemm_proj(const u16* __restrict__ A,
                                                  const u16* __restrict__ Bt,
                                                  const u16* __restrict__ bias,
                                                  u16* __restrict__ C) {
    __shared__ __align__(16) u16 lds_a[2 * 4096];
    __shared__ __align__(16) u16 lds_b[2 * 4096];
    MF_IDS();
    const int bm = blockIdx.x * 128, bn = blockIdx.y * 128;
    const u16* a0 = A + (size_t)(bm + sr) * 768 + sc;
    const u16* b0 = Bt + (size_t)(bn + sr) * 768 + sc;
    auto stage = [&](int buf, int kb) {
        u16* base_a = lds_a + buf * 4096 + tid * 8;
        u16* base_b = lds_b + buf * 4096 + tid * 8;
        gll16(a0 + kb, base_a);
        gll16(a0 + (size_t)64 * 768 + kb, base_a + 2048);
        gll16(b0 + kb, base_b);
        gll16(b0 + (size_t)64 * 768 + kb, base_b + 2048);
    };
    stage(0, 0);
    __syncthreads();
    for (int kb = 0; kb < 768; kb += 32) {
        const int cur = (kb >> 5) & 1;
        if (kb + 32 < 768) stage(cur ^ 1, kb + 32);
        MF_MFMA_BUF(cur);
        __syncthreads();
    }
#pragma unroll
    for (int i = 0; i < 4; ++i)
#pragma unroll
        for (int j = 0; j < 4; ++j) {
            int col = bn + wn * 64 + j * 16 + lcol;
            float bv = bf2f(bias[col]);
#pragma unroll
            for (int r = 0; r < 4; ++r) {
                int row = bm + wm * 64 + i * 16 + quad * 4 + r;
                float v = acc[i][j][r] + bv;
                C[(size_t)row * 1536 + col] = f2bf(v > 0.f ? v : 0.f);
            }
        }
}

// ---------- GEMM 1b: P[z] = rproj[:, z*768:] @ out_w[:, z*768:]^T (+bias z=0)
// M2048 N768 K768, grid (16,6,2). Output f32, no relu (gather commutes with
// the GEMM; gather-add happens in mgemm_out's epilogue).
__global__ __launch_bounds__(256) void mgemm_p01(const u16* __restrict__ RP,
                                                 const u16* __restrict__ W,
                                                 const u16* __restrict__ bias,
                                                 float* __restrict__ P) {
    __shared__ __align__(16) u16 lds_a[2 * 4096];
    __shared__ __align__(16) u16 lds_b[2 * 4096];
    MF_IDS();
    const int z = blockIdx.z;
    const int bm = blockIdx.x * 128, bn = blockIdx.y * 128;
    const u16* a0 = RP + (size_t)(bm + sr) * 1536 + z * 768 + sc;
    const u16* b0 = W + (size_t)(bn + sr) * 2304 + z * 768 + sc;
    auto stage = [&](int buf, int kb) {
        u16* base_a = lds_a + buf * 4096 + tid * 8;
        u16* base_b = lds_b + buf * 4096 + tid * 8;
        gll16(a0 + kb, base_a);
        gll16(a0 + (size_t)64 * 1536 + kb, base_a + 2048);
        gll16(b0 + kb, base_b);
        gll16(b0 + (size_t)64 * 2304 + kb, base_b + 2048);
    };
    stage(0, 0);
    __syncthreads();
    for (int kb = 0; kb < 768; kb += 32) {
        const int cur = (kb >> 5) & 1;
        if (kb + 32 < 768) stage(cur ^ 1, kb + 32);
        MF_MFMA_BUF(cur);
        __syncthreads();
    }
    float* Pz = P + (size_t)z * 2048 * 768;
#pragma unroll
    for (int i = 0; i < 4; ++i)
#pragma unroll
        for (int j = 0; j < 4; ++j) {
            int col = bn + wn * 64 + j * 16 + lcol;
            float bv = (z == 0) ? bf2f(bias[col]) : 0.f;
#pragma unroll
            for (int r = 0; r < 4; ++r) {
                int row = bm + wm * 64 + i * 16 + quad * 4 + r;
                Pz[(size_t)row * 768 + col] = acc[i][j][r] + bv;
            }
        }
}

// ---------- GEMM 2a: per-j conv contributions (raw, no relu) ----------------
__global__ __launch_bounds__(256) void mgemm_convc(const u16* __restrict__ H,
                                                   const u16* __restrict__ Bt2,
                                                   u16* __restrict__ Cv) {
    __shared__ __align__(16) u16 lds_a[2 * 4096];
    __shared__ __align__(16) u16 lds_b[2 * 4096];
    MF_IDS();
    const int j = blockIdx.z;
    const int bm = blockIdx.x * 128, bn = blockIdx.y * 128;
    const int row0 = bm + sr, row1 = row0 + 64;
    const int l0 = row0 & (Lsz - 1), l1 = row1 & (Lsz - 1);
    const u16* a0 = H + (size_t)(row0 + j) * 768 + sc;
    const u16* a1 = H + (size_t)(row1 + j) * 768 + sc;
    const u16* b0 = Bt2 + (size_t)(bn + sr) * Kconv + (size_t)j * 768 + sc;
    const bool v0 = (l0 + j < Lsz), v1 = (l1 + j < Lsz);
    const uint4 zero = {0u, 0u, 0u, 0u};
    if (!v0) { *(uint4*)(lds_a + tid * 8) = zero; *(uint4*)(lds_a + 4096 + tid * 8) = zero; }
    if (!v1) { *(uint4*)(lds_a + 2048 + tid * 8) = zero; *(uint4*)(lds_a + 4096 + 2048 + tid * 8) = zero; }
    auto stage = [&](int buf, int kb) {
        u16* base_a = lds_a + buf * 4096 + tid * 8;
        u16* base_b = lds_b + buf * 4096 + tid * 8;
        if (v0) gll16(a0 + kb, base_a);
        if (v1) gll16(a1 + kb, base_a + 2048);
        gll16(b0 + kb, base_b);
        gll16(b0 + (size_t)64 * Kconv + kb, base_b + 2048);
    };
    stage(0, 0);
    __syncthreads();
    for (int kb = 0; kb < 768; kb += 32) {
        const int cur = (kb >> 5) & 1;
        if (kb + 32 < 768) stage(cur ^ 1, kb + 32);
        MF_MFMA_BUF(cur);
        __syncthreads();
    }
#pragma unroll
    for (int i = 0; i < 4; ++i)
#pragma unroll
        for (int jj = 0; jj < 4; ++jj) {
            int col = bn + wn * 64 + jj * 16 + lcol;
#pragma unroll
            for (int r = 0; r < 4; ++r) {
                int row = bm + wm * 64 + i * 16 + quad * 4 + r;
                Cv[((size_t)row * Wsz + j) * 768 + col] = f2bf(acc[i][jj][r]);
            }
        }
}

// ---------- GEMM 2b: in-place running sum over j + relu --------------------
__global__ __launch_bounds__(256) void cumsum_relu(u16* __restrict__ Cv) {
    int idx = blockIdx.x * 256 + threadIdx.x;
    const int total = (Bsz * Lsz) * (Dsz / 8);
    if (idx >= total) return;
    int m = idx / (Dsz / 8);
    int c = (idx % (Dsz / 8)) * 8;
    u16* p = Cv + (size_t)m * Wsz * 768 + c;
    float s[8] = {0.f, 0.f, 0.f, 0.f, 0.f, 0.f, 0.f, 0.f};
#pragma unroll
    for (int j = 0; j < Wsz; ++j) {
        uint4 t = *(const uint4*)(p + (size_t)j * 768);
        const u16* q = (const u16*)&t;
        uint4 o;
        u16* qo = (u16*)&o;
#pragma unroll
        for (int i = 0; i < 8; ++i) {
            s[i] += bf2f(q[i]);
            qo[i] = f2bf(s[i] > 0.f ? s[i] : 0.f);
        }
        *(uint4*)(p + (size_t)j * 768) = o;
    }
}

// ---------- GEMM 3: out = relu(rconv_relu @ W3^T + P0[s0] + P1[s1]) ---------
// M24576 N768 K768; A rows are identity-indexed rconv (no gather); span
// gathers became epilogue row-adds from f32 P (bias folded into P0).
__global__ __launch_bounds__(256) void mgemm_out(const u16* __restrict__ RC,
                                                 const int* __restrict__ SPn,
                                                 const u16* __restrict__ W,
                                                 const float* __restrict__ P,
                                                 void* __restrict__ out,
                                                 const int* __restrict__ flags) {
    __shared__ __align__(16) u16 lds_a[2 * 4096];
    __shared__ __align__(16) u16 lds_b[2 * 4096];
    __shared__ u32 off0[128], off1[128];
    MF_IDS();
    const int bm = blockIdx.x * 128, bn = blockIdx.y * 128;
    if (tid < 128) {
        int n = bm + tid;
        int b = n / LWsz;
        off0[tid] = (u32)((b * Lsz + SPn[2 * n]) * 768);
        off1[tid] = (u32)((b * Lsz + SPn[2 * n + 1]) * 768);
    }
    const u16* a0 = RC + (size_t)(bm + sr) * 768 + sc;
    const u16* b0 = W + (size_t)(bn + sr) * 2304 + 1536 + sc;
    auto stage = [&](int buf, int kb) {
        u16* base_a = lds_a + buf * 4096 + tid * 8;
        u16* base_b = lds_b + buf * 4096 + tid * 8;
        gll16(a0 + kb, base_a);
        gll16(a0 + (size_t)64 * 768 + kb, base_a + 2048);
        gll16(b0 + kb, base_b);
        gll16(b0 + (size_t)64 * 2304 + kb, base_b + 2048);
    };
    stage(0, 0);
    __syncthreads();
    for (int kb = 0; kb < 768; kb += 32) {
        const int cur = (kb >> 5) & 1;
        if (kb + 32 < 768) stage(cur ^ 1, kb + 32);
        MF_MFMA_BUF(cur);
        __syncthreads();
    }
    const float* P1 = P + (size_t)2048 * 768;
    const int isf32 = flags[0];
#pragma unroll
    for (int i = 0; i < 4; ++i)
#pragma unroll
        for (int j = 0; j < 4; ++j) {
            int col = bn + wn * 64 + j * 16 + lcol;
#pragma unroll
            for (int r = 0; r < 4; ++r) {
                int rl = wm * 64 + i * 16 + quad * 4 + r;
                int row = bm + rl;
                float v = acc[i][j][r] + P[(size_t)off0[rl] + col] + P1[(size_t)off1[rl] + col];
                v = v > 0.f ? v : 0.f;
                if (isf32) ((float*)out)[(size_t)row * 768 + col] = v;
                else       ((u16*)out)[(size_t)row * 768 + col] = f2bf(v);
            }
        }
}

extern "C" void kernel_launch(void* const* d_in, const int* in_sizes, int n_in,
                              void* d_out, int out_size, void* d_ws, size_t ws_size,
                              hipStream_t stream) {
    const void* h      = d_in[0];
    const void* span   = d_in[1];
    const void* proj_w = d_in[2];
    const void* proj_b = d_in[3];
    const void* conv_w = d_in[4];
    const void* out_w  = d_in[5];
    const void* out_b  = d_in[6];

    char* p = (char*)d_ws;
    int* flags = (int*)p;                 p += 64;
    u16* ch    = (u16*)p;                 p += (size_t)Nh   * 2;   // pack_all dst base
    u16* cpw   = (u16*)p;                 p += (size_t)Npw  * 2;
    u16* cpb   = (u16*)p;                 p += (size_t)Npb  * 2;
    u16* cow   = (u16*)p;                 p += (size_t)Now  * 2;
    u16* cob   = (u16*)p;                 p += (size_t)Nob  * 2;
    u16* bt2   = (u16*)p;                 p += (size_t)Nbt2 * 2;   // 14.2 MB
    u16* rproj = (u16*)p;                 p += (size_t)Nrp  * 2;
    u16* rconv = (u16*)p;                 p += (size_t)Nrc  * 2;
    int* cspan = (int*)p;
    // P (2 x 2048 x 768 f32 = 12.6 MB) aliases bt2: bt2 is dead after
    // mgemm_convc, and mgemm_p01 is launched after it (stream-ordered).
    float* Pbuf = (float*)bt2;

    detect_k<<<1, 256, 0, stream>>>((const u32*)h, (const u32*)span, flags);

    pack_all<<<(PTOT / 4 + 255) / 256, 256, 0, stream>>>(h, proj_w, proj_b,
                                                         out_w, out_b, ch, flags);
    pack_conv<<<(Nbt2 + 255) / 256, 256, 0, stream>>>(conv_w, bt2, flags);
    pack_span<<<(Nsp + 255) / 256, 256, 0, stream>>>((const int*)span, cspan, flags);

    mgemm_proj<<<dim3(16, 12), 256, 0, stream>>>(ch, cpw, cpb, rproj);
    mgemm_convc<<<dim3(16, 6, 12), 256, 0, stream>>>(ch, bt2, rconv);
    mgemm_p01<<<dim3(16, 6, 2), 256, 0, stream>>>(rproj, cow, cob, Pbuf);
    cumsum_relu<<<((Bsz * Lsz) * (Dsz / 8) + 255) / 256, 256, 0, stream>>>(rconv);
    mgemm_out<<<dim3(192, 6), 256, 0, stream>>>(rconv, cspan, cow, Pbuf,
                                                d_out, flags);
}